// Round 2
// baseline (932.243 us; speedup 1.0000x reference)
//
#include <hip/hip_runtime.h>
#include <hip/hip_bf16.h>

// Problem constants
#define NQ     16384       // 4*16*16*16 query vectors
#define EDIM   256
#define NE     8192
#define LHW    4096        // 16*16*16
#define BETA   0.25f

// d_out layout (float32), derived from out_size at launch:
//  [0, ZQN)           z_q_out  (b,c,l,h,w)   ZQN = 4*256*4096 = 4194304
//  [ZQN+0]            loss
//  [ZQN+1]            perplexity
//  [ZQN+2]            unique (as float)
//  [ZQN+3, +16384)    idx (as float)

// ws layout
#define WS_BEST    0          // u64[16384]  = 131072 B
#define WS_CNT     131072     // u32[8192]   = 32768 B
#define WS_LOSS    164096     // float
#define WS_WSQ     164352     // float[8192] = 32768 B

__device__ __forceinline__ unsigned f32_sortable(float f) {
    unsigned b = __float_as_uint(f);
    return (b & 0x80000000u) ? ~b : (b | 0x80000000u);
}

// K1: wsq[e] = sum_d w[e][d]^2 (f64 accumulate to minimize argmin tie flips).
// One wave per row.
__global__ __launch_bounds__(256) void wsq_kernel(const float* __restrict__ w,
                                                  float* __restrict__ wsq) {
    int wave = threadIdx.x >> 6, lane = threadIdx.x & 63;
    int row = blockIdx.x * 4 + wave;
    float4 v = *(const float4*)(w + (size_t)row * EDIM + lane * 4);
    double s = (double)v.x * v.x + (double)v.y * v.y +
               (double)v.z * v.z + (double)v.w * v.w;
    #pragma unroll
    for (int off = 32; off; off >>= 1) s += __shfl_xor(s, off, 64);
    if (lane == 0) wsq[row] = (float)s;
}

// K2: distances + fused argmin.
// Block tile: 128 n x 128 e, looping 16 e-tiles (2048 e per block), K in 8 chunks of 32.
// grid = (4 e-splits, 128 n-tiles), 256 threads, thread tile 8n x 8e.
// z layout: z[b][c][lhw] -> zf[n][k] at b*1048576 + k*4096 + (n&4095)
__global__ __launch_bounds__(256, 2) void dist_kernel(const float* __restrict__ z,
                                                      const float* __restrict__ w,
                                                      const float* __restrict__ wsq,
                                                      unsigned long long* __restrict__ best) {
    __shared__ float lds_a[32 * 128];   // [k][n]
    __shared__ float lds_b[32 * 132];   // [k][e] padded (+4)
    int tid = threadIdx.x;
    int tx = tid & 15, ty = tid >> 4;   // tx -> e, ty -> n
    int n0 = blockIdx.y * 128;
    int bb_ = n0 >> 12, lhw0 = n0 & 4095;
    const float* zb = z + (size_t)bb_ * (EDIM * LHW) + lhw0;
    int ebase = blockIdx.x * 2048;

    unsigned long long runmin[8];
    #pragma unroll
    for (int i = 0; i < 8; ++i) runmin[i] = ~0ull;

    float acc[64];
    for (int et = 0; et < 16; ++et) {
        int e0 = ebase + et * 128;
        #pragma unroll
        for (int i = 0; i < 64; ++i) acc[i] = 0.f;
        for (int kc = 0; kc < 8; ++kc) {
            int k0 = kc * 32;
            // stage A: 128n x 32k, float4 along n -> lds_a[k][n]
            #pragma unroll
            for (int p = 0; p < 4; ++p) {
                int f = p * 256 + tid;
                int kk = f >> 5, nn4 = f & 31;
                float4 v = *(const float4*)(zb + (size_t)(k0 + kk) * LHW + nn4 * 4);
                *((float4*)(lds_a + kk * 128 + nn4 * 4)) = v;
            }
            // stage B: 128e x 32k, float4 along k -> transposed into lds_b[k][e]
            #pragma unroll
            for (int p = 0; p < 4; ++p) {
                int f = p * 256 + tid;
                int ee = f >> 3, kk4 = f & 7;
                float4 v = *(const float4*)(w + (size_t)(e0 + ee) * EDIM + k0 + kk4 * 4);
                lds_b[(kk4 * 4 + 0) * 132 + ee] = v.x;
                lds_b[(kk4 * 4 + 1) * 132 + ee] = v.y;
                lds_b[(kk4 * 4 + 2) * 132 + ee] = v.z;
                lds_b[(kk4 * 4 + 3) * 132 + ee] = v.w;
            }
            __syncthreads();
            #pragma unroll
            for (int k = 0; k < 32; ++k) {
                float a[8], bv[8];
                *(float4*)(a)     = *(float4*)(lds_a + k * 128 + ty * 8);
                *(float4*)(a + 4) = *(float4*)(lds_a + k * 128 + ty * 8 + 4);
                *(float4*)(bv)     = *(float4*)(lds_b + k * 132 + tx * 8);
                *(float4*)(bv + 4) = *(float4*)(lds_b + k * 132 + tx * 8 + 4);
                #pragma unroll
                for (int i = 0; i < 8; ++i)
                    #pragma unroll
                    for (int j = 0; j < 8; ++j)
                        acc[i * 8 + j] = fmaf(a[i], bv[j], acc[i * 8 + j]);
            }
            __syncthreads();
        }
        // epilogue: d = wsq[e] - 2*dot  (||z||^2 constant per n, dropped)
        #pragma unroll
        for (int i = 0; i < 8; ++i) {
            unsigned long long m = runmin[i];
            #pragma unroll
            for (int j = 0; j < 8; ++j) {
                int e = e0 + tx * 8 + j;
                float d = wsq[e] - 2.0f * acc[i * 8 + j];
                unsigned long long key =
                    ((unsigned long long)f32_sortable(d) << 32) | (unsigned)e;
                m = (m < key) ? m : key;
            }
            runmin[i] = m;
        }
    }
    // reduce across 16 tx lanes sharing each (ty, i), then one atomic per n
    #pragma unroll
    for (int i = 0; i < 8; ++i) {
        unsigned long long kk = runmin[i];
        #pragma unroll
        for (int off = 8; off >= 1; off >>= 1) {
            unsigned long long o = __shfl_xor(kk, off, 16);
            kk = (kk < o) ? kk : o;
        }
        if (tx == 0) atomicMin(&best[n0 + ty * 8 + i], kk);
    }
}

// K3: gather codebook rows, transpose-write z_q_st, loss partials, histogram, idx out.
// One block per 64 n.
__global__ __launch_bounds__(256) void gather_kernel(const float* __restrict__ z,
                                                     const float* __restrict__ w,
                                                     const unsigned long long* __restrict__ best,
                                                     unsigned* __restrict__ counts,
                                                     float* __restrict__ loss,
                                                     float* __restrict__ out,
                                                     float* __restrict__ out_idx) {
    __shared__ int idx_s[64];
    __shared__ float wl[64 * 257];
    int tid = threadIdx.x;
    int n0 = blockIdx.x * 64;
    if (tid < 64) {
        unsigned long long k = best[n0 + tid];
        int idx = ((int)(unsigned)(k & 0xFFFFFFFFull)) & (NE - 1);  // mask = OOB guard
        idx_s[tid] = idx;
        out_idx[n0 + tid] = (float)idx;
        atomicAdd(&counts[idx], 1u);
    }
    __syncthreads();
    for (int i = 0; i < 64; ++i)
        wl[i * 257 + tid] = w[(size_t)idx_s[i] * EDIM + tid];
    __syncthreads();
    int tn = tid & 63, tc = tid >> 6;
    int bb_ = n0 >> 12, lhw0 = n0 & 4095;
    size_t zb = (size_t)bb_ * (EDIM * LHW) + lhw0 + tn;
    float accl = 0.f;
    for (int cc = 0; cc < 64; ++cc) {
        int c = tc * 64 + cc;
        float wv = wl[tn * 257 + c];
        size_t a = zb + (size_t)c * LHW;
        float zv = z[a];
        float diff = wv - zv;            // z_q - zc
        out[a] = zv + diff;              // replicate zc + (z_q - zc) rounding
        accl += diff * diff;
    }
    #pragma unroll
    for (int off = 32; off; off >>= 1) accl += __shfl_xor(accl, off, 64);
    if ((tid & 63) == 0) atomicAdd(loss, accl);
}

// K4: scalars
__global__ __launch_bounds__(256) void finalize_kernel(const unsigned* __restrict__ counts,
                                                       const float* __restrict__ loss,
                                                       float* __restrict__ out_scalars) {
    __shared__ float ss[4];
    __shared__ int uu[4];
    int tid = threadIdx.x;
    float s = 0.f;
    int uniq = 0;
    for (int i = tid; i < NE; i += 256) {
        unsigned c = counts[i];
        if (c > 0) {
            float p = (float)c * (1.0f / (float)NQ);
            s += p * logf(p + 1e-10f);
            uniq++;
        }
    }
    #pragma unroll
    for (int off = 32; off; off >>= 1) {
        s += __shfl_xor(s, off, 64);
        uniq += __shfl_xor(uniq, off, 64);
    }
    int wave = tid >> 6;
    if ((tid & 63) == 0) { ss[wave] = s; uu[wave] = uniq; }
    __syncthreads();
    if (tid == 0) {
        float st = ss[0] + ss[1] + ss[2] + ss[3];
        int ut = uu[0] + uu[1] + uu[2] + uu[3];
        out_scalars[0] = BETA * loss[0] * (1.0f / (float)(NQ * EDIM));  // loss
        out_scalars[1] = expf(-st);                                     // perplexity
        out_scalars[2] = (float)ut;                                     // unique
    }
}

extern "C" void kernel_launch(void* const* d_in, const int* in_sizes, int n_in,
                              void* d_out, int out_size, void* d_ws, size_t ws_size,
                              hipStream_t stream) {
    const float* z = (const float*)d_in[0];
    const float* w = (const float*)d_in[1];
    float* out = (float*)d_out;
    char* ws = (char*)d_ws;
    unsigned long long* best = (unsigned long long*)(ws + WS_BEST);
    unsigned* counts = (unsigned*)(ws + WS_CNT);
    float* loss = (float*)(ws + WS_LOSS);
    float* wsq = (float*)(ws + WS_WSQ);

    // Output offsets derived from out_size:
    // [0, zqn) z_q, then loss, perplexity, unique, then idx[NQ].
    int idx_off = out_size - NQ;       // 4194307
    int scal_off = idx_off - 3;        // 4194304 (= end of z_q region)
    float* out_idx = out + idx_off;
    float* out_scalars = out + scal_off;

    hipMemsetAsync(best, 0xFF, NQ * sizeof(unsigned long long), stream);
    hipMemsetAsync(counts, 0, NE * sizeof(unsigned), stream);
    hipMemsetAsync(loss, 0, sizeof(float), stream);

    wsq_kernel<<<NE / 4, 256, 0, stream>>>(w, wsq);
    dist_kernel<<<dim3(4, 128), 256, 0, stream>>>(z, w, wsq, best);
    gather_kernel<<<NQ / 64, 256, 0, stream>>>(z, w, best, counts, loss, out, out_idx);
    finalize_kernel<<<1, 256, 0, stream>>>(counts, loss, out_scalars);
}